// Round 3
// baseline (116.554 us; speedup 1.0000x reference)
//
#include <hip/hip_runtime.h>
#include <hip/hip_bf16.h>

#define VOCABSZ 50257
#define BASEDIM 64
#define ND 16
#define NTOK (16 * 8192)
#define CAP 4096            // per-domain vocab bucket capacity (max ~1700 actual)
#define NBLK2 8             // blocks per domain in the MLP kernel

typedef __attribute__((ext_vector_type(8))) short short8;
typedef __attribute__((ext_vector_type(4))) float f32x4;

__device__ __forceinline__ short f2bf(float f) {
    union { float f; unsigned u; } v; v.f = f;
    unsigned r = (v.u + 0x7FFFu + ((v.u >> 16) & 1u)) >> 16;  // RNE f32->bf16
    return (short)r;
}

// Kernel 1: bucket VOCAB ids by domain (two-level atomics, only 197*16 global
// atomics) and copy unassigned rows emb[v] -> table[v] with float4.
__global__ __launch_bounds__(256) void k_vbucket(
    const int* __restrict__ tdom, const float* __restrict__ emb,
    float* __restrict__ table, int* __restrict__ g_cnt, int* __restrict__ bucket)
{
    __shared__ int sm_d[256];
    __shared__ int sm_cnt[ND];
    __shared__ int sm_base[ND];

    const int lt = threadIdx.x;
    const int v0 = blockIdx.x * 256;
    const int v  = v0 + lt;

    if (lt < ND) sm_cnt[lt] = 0;
    __syncthreads();

    int d = 0x7fffffff;
    if (v < VOCABSZ) d = tdom[v];
    sm_d[lt] = d;
    int pos = -1;
    if (d < ND) pos = atomicAdd(&sm_cnt[d], 1);
    __syncthreads();

    if (lt < ND) sm_base[lt] = atomicAdd(&g_cnt[lt], sm_cnt[lt]);
    __syncthreads();

    if (d < ND) {
        const int gp = sm_base[d] + pos;
        if (gp < CAP) bucket[d * CAP + gp] = v;
    }

    // Copy unassigned rows (they get no correction): 16-lane groups, float4.
    const int g = lt >> 4, l16 = lt & 15;
    const float4* ev = (const float4*)emb;
    float4* tv = (float4*)table;
    #pragma unroll
    for (int it = 0; it < 16; ++it) {
        const int li = it * 16 + g;
        const int vv = v0 + li;
        if (vv < VOCABSZ && sm_d[li] >= ND)
            tv[(size_t)vv * 16 + l16] = ev[(size_t)vv * 16 + l16];
    }
}

// Kernel 2: per-domain MLP correction on VOCAB rows via MFMA (verified
// fragment layout from R0). table[v] = emb[v] + 0.1 * W2(gelu(W1 emb[v])).
__global__ __launch_bounds__(256) void k_vcorrect(
    const float* __restrict__ emb, const float* __restrict__ W1,
    const float* __restrict__ W2, const int* __restrict__ g_cnt,
    const int* __restrict__ bucket, float* __restrict__ table)
{
    const int blk   = blockIdx.x;
    const int d     = blk / NBLK2;
    const int chunk = blk % NBLK2;
    int cnt = g_cnt[d];
    if (cnt > CAP) cnt = CAP;

    const int wave = threadIdx.x >> 6;
    const int lane = threadIdx.x & 63;
    const int kr   = (lane >> 4) * 8;      // k-octet base within a 32-K tile
    const int nco  = lane & 15;

    // W1[d], W2[d] as MFMA B-fragments (bf16), 64 VGPRs total.
    const float* w1 = W1 + (size_t)d * 4096;
    const float* w2 = W2 + (size_t)d * 4096;
    short8 fw1[8], fw2[8];
    #pragma unroll
    for (int kt = 0; kt < 2; ++kt) {
        #pragma unroll
        for (int nt = 0; nt < 4; ++nt) {
            short8 a, b;
            #pragma unroll
            for (int i = 0; i < 8; ++i) {
                const int k = kt * 32 + kr + i;
                const int n = nt * 16 + nco;
                a[i] = f2bf(w1[k * 64 + n]);
                b[i] = f2bf(w2[k * 64 + n]);
            }
            fw1[kt * 4 + nt] = a;
            fw2[kt * 4 + nt] = b;
        }
    }

    // Per-wave hid staging: [16 rows][stride 72 bf16] (pad avoids conflicts).
    __shared__ __align__(16) short sm_hid[4][16 * 72];
    short* hidb = &sm_hid[wave][0];

    const int* buck = bucket + (size_t)d * CAP;

    for (int base = chunk * 64; base < cnt; base += NBLK2 * 64) {
        const int s0 = base + wave * 16;
        int rem = cnt - s0;
        if (rem <= 0) continue;            // per-wave; no barriers in loop
        if (rem > 16) rem = 16;

        // Gather emb rows as A-fragments (row m = lane&15).
        const int m_idx = s0 + (nco < rem ? nco : rem - 1);
        const int vm = buck[m_idx];
        const float* hrow = emb + (size_t)vm * 64;
        short8 ha[2];
        #pragma unroll
        for (int kt = 0; kt < 2; ++kt) {
            const float4* hv = (const float4*)(hrow + kt * 32 + kr);
            const float4 p = hv[0], q = hv[1];
            short8 t;
            t[0] = f2bf(p.x); t[1] = f2bf(p.y); t[2] = f2bf(p.z); t[3] = f2bf(p.w);
            t[4] = f2bf(q.x); t[5] = f2bf(q.y); t[6] = f2bf(q.z); t[7] = f2bf(q.w);
            ha[kt] = t;
        }

        // hid_pre = H @ W1
        f32x4 acc[4];
        #pragma unroll
        for (int nt = 0; nt < 4; ++nt) {
            acc[nt] = (f32x4){0.f, 0.f, 0.f, 0.f};
            acc[nt] = __builtin_amdgcn_mfma_f32_16x16x32_bf16(ha[0], fw1[nt],     acc[nt], 0, 0, 0);
            acc[nt] = __builtin_amdgcn_mfma_f32_16x16x32_bf16(ha[1], fw1[4 + nt], acc[nt], 0, 0, 0);
        }

        // exact GELU -> bf16 hid in LDS ([m][c] layout)
        #pragma unroll
        for (int nt = 0; nt < 4; ++nt) {
            #pragma unroll
            for (int i = 0; i < 4; ++i) {
                const float v  = acc[nt][i];
                const float gv = 0.5f * v * (1.0f + erff(v * 0.70710678118f));
                const int  mm  = (lane >> 4) * 4 + i;
                const int  c   = nt * 16 + nco;
                hidb[mm * 72 + c] = f2bf(gv);
            }
        }
        asm volatile("s_waitcnt lgkmcnt(0)" ::: "memory");

        // Re-read as A-fragments.
        short8 pa[2];
        #pragma unroll
        for (int kt = 0; kt < 2; ++kt)
            pa[kt] = *(const short8*)&hidb[(lane & 15) * 72 + kt * 32 + kr];

        // corr = gelu(hid) @ W2
        f32x4 acc2[4];
        #pragma unroll
        for (int nt = 0; nt < 4; ++nt) {
            acc2[nt] = (f32x4){0.f, 0.f, 0.f, 0.f};
            acc2[nt] = __builtin_amdgcn_mfma_f32_16x16x32_bf16(pa[0], fw2[nt],     acc2[nt], 0, 0, 0);
            acc2[nt] = __builtin_amdgcn_mfma_f32_16x16x32_bf16(pa[1], fw2[4 + nt], acc2[nt], 0, 0, 0);
        }

        // table[v] = emb[v] + 0.1 * corr
        #pragma unroll
        for (int i = 0; i < 4; ++i) {
            const int mm = (lane >> 4) * 4 + i;
            if (mm < rem) {
                const int vv = buck[s0 + mm];
                const float* hr = emb + (size_t)vv * 64;
                float* trow = table + (size_t)vv * 64;
                #pragma unroll
                for (int nt = 0; nt < 4; ++nt) {
                    const int c = nt * 16 + nco;
                    trow[c] = hr[c] + 0.1f * acc2[nt][i];
                }
            }
        }
    }
}

// Kernel 3: pure gather. out[t] = table[x[t]], 16 lanes x float4 per row.
__global__ __launch_bounds__(256) void k_gather(
    const int* __restrict__ x, const float* __restrict__ table,
    float* __restrict__ out)
{
    const int idx = blockIdx.x * 256 + threadIdx.x;
    const int row = idx >> 4, l16 = idx & 15;
    const int xr  = x[row];
    ((float4*)out)[(size_t)row * 16 + l16] =
        ((const float4*)table)[(size_t)xr * 16 + l16];
}

extern "C" void kernel_launch(void* const* d_in, const int* in_sizes, int n_in,
                              void* d_out, int out_size, void* d_ws, size_t ws_size,
                              hipStream_t stream) {
    const int*   x    = (const int*)d_in[0];
    const int*   tdom = (const int*)d_in[1];
    const float* emb  = (const float*)d_in[2];
    const float* W1   = (const float*)d_in[3];
    const float* W2   = (const float*)d_in[4];
    float* out = (float*)d_out;

    int*   g_cnt  = (int*)d_ws;                              // 64 B
    int*   bucket = (int*)((char*)d_ws + 1024);              // 16*CAP*4 = 256 KB
    float* table  = (float*)((char*)d_ws + (1u << 20));      // 12.9 MB

    hipMemsetAsync(d_ws, 0, ND * sizeof(int), stream);
    hipLaunchKernelGGL(k_vbucket, dim3((VOCABSZ + 255) / 256), dim3(256), 0,
                       stream, tdom, emb, table, g_cnt, bucket);
    hipLaunchKernelGGL(k_vcorrect, dim3(ND * NBLK2), dim3(256), 0, stream,
                       emb, W1, W2, g_cnt, bucket, table);
    hipLaunchKernelGGL(k_gather, dim3(NTOK * 16 / 256), dim3(256), 0, stream,
                       x, table, out);
}

// Round 9
// 110.521 us; speedup vs baseline: 1.0546x; 1.0546x over previous
//
#include <hip/hip_runtime.h>
#include <hip/hip_bf16.h>

#define VOCABSZ 50257
#define BASEDIM 64
#define ND 16
#define NTOK (16 * 8192)
#define CAP 4096            // per-domain vocab bucket capacity (max ~1700 actual)
#define NBLK2 16            // blocks per domain in the MLP kernel (256 total)
#define CNT_STRIDE 16       // counter padding: 16 ints = 64B, one line each

typedef __attribute__((ext_vector_type(8))) short short8;
typedef __attribute__((ext_vector_type(4))) float f32x4;

__device__ __forceinline__ short f2bf(float f) {
    union { float f; unsigned u; } v; v.f = f;
    unsigned r = (v.u + 0x7FFFu + ((v.u >> 16) & 1u)) >> 16;  // RNE f32->bf16
    return (short)r;
}

// Kernel 1: bucket VOCAB ids by domain (two-level atomics; global counters
// padded to one cache line each) and copy unassigned rows emb[v] -> table[v].
__global__ __launch_bounds__(256) void k_vbucket(
    const int* __restrict__ tdom, const float* __restrict__ emb,
    float* __restrict__ table, int* __restrict__ g_cnt, int* __restrict__ bucket)
{
    __shared__ int sm_d[256];
    __shared__ int sm_cnt[ND];
    __shared__ int sm_base[ND];

    const int lt = threadIdx.x;
    const int v0 = blockIdx.x * 256;
    const int v  = v0 + lt;

    if (lt < ND) sm_cnt[lt] = 0;
    __syncthreads();

    int d = 0x7fffffff;
    if (v < VOCABSZ) d = tdom[v];
    sm_d[lt] = d;
    int pos = -1;
    if (d < ND) pos = atomicAdd(&sm_cnt[d], 1);
    __syncthreads();

    if (lt < ND) sm_base[lt] = atomicAdd(&g_cnt[lt * CNT_STRIDE], sm_cnt[lt]);
    __syncthreads();

    if (d < ND) {
        const int gp = sm_base[d] + pos;
        if (gp < CAP) bucket[d * CAP + gp] = v;
    }

    // Copy unassigned rows (no correction): 16-lane groups, float4.
    const int g = lt >> 4, l16 = lt & 15;
    const float4* ev = (const float4*)emb;
    float4* tv = (float4*)table;
    #pragma unroll
    for (int it = 0; it < 16; ++it) {
        const int li = it * 16 + g;
        const int vv = v0 + li;
        if (vv < VOCABSZ && sm_d[li] >= ND)
            tv[(size_t)vv * 16 + l16] = ev[(size_t)vv * 16 + l16];
    }
}

// Kernel 2: per-domain MLP correction on VOCAB rows via MFMA.
// table[v] = emb[v] + 0.1 * W2(gelu(W1 emb[v])).
// Weights staged to LDS with coalesced float4 loads; fragments pulled from LDS.
__global__ __launch_bounds__(256) void k_vcorrect(
    const float* __restrict__ emb, const float* __restrict__ W1,
    const float* __restrict__ W2, const int* __restrict__ g_cnt,
    const int* __restrict__ bucket, float* __restrict__ table)
{
    const int blk   = blockIdx.x;
    const int d     = blk / NBLK2;
    const int chunk = blk % NBLK2;
    int cnt = g_cnt[d * CNT_STRIDE];
    if (cnt > CAP) cnt = CAP;

    const int wave = threadIdx.x >> 6;
    const int lane = threadIdx.x & 63;
    const int kr   = (lane >> 4) * 8;      // k-octet base within a 32-K tile
    const int nco  = lane & 15;

    __shared__ float sw[2][4096];                      // W1,W2 raw fp32 (32 KB)
    __shared__ __align__(16) short sm_hid[4][16 * 72]; // hid staging (9 KB)

    // Coalesced cooperative weight load: 1024 float4 per matrix.
    {
        const float4* w1v = (const float4*)(W1 + (size_t)d * 4096);
        const float4* w2v = (const float4*)(W2 + (size_t)d * 4096);
        float4* s1 = (float4*)sw[0];
        float4* s2 = (float4*)sw[1];
        for (int i = threadIdx.x; i < 1024; i += 256) {
            s1[i] = w1v[i];
            s2[i] = w2v[i];
        }
    }
    __syncthreads();

    // Extract MFMA B-fragments (bf16) from LDS. 64 VGPRs total.
    short8 fw1[8], fw2[8];
    #pragma unroll
    for (int kt = 0; kt < 2; ++kt) {
        #pragma unroll
        for (int nt = 0; nt < 4; ++nt) {
            short8 a, b;
            #pragma unroll
            for (int i = 0; i < 8; ++i) {
                const int k = kt * 32 + kr + i;
                const int n = nt * 16 + nco;
                a[i] = f2bf(sw[0][k * 64 + n]);
                b[i] = f2bf(sw[1][k * 64 + n]);
            }
            fw1[kt * 4 + nt] = a;
            fw2[kt * 4 + nt] = b;
        }
    }

    short* hidb = &sm_hid[wave][0];
    const int* buck = bucket + (size_t)d * CAP;

    for (int base = chunk * 64; base < cnt; base += NBLK2 * 64) {
        const int s0 = base + wave * 16;
        int rem = cnt - s0;
        if (rem <= 0) continue;            // per-wave; no barriers in loop
        if (rem > 16) rem = 16;

        // Gather emb rows as A-fragments (row m = lane&15).
        const int m_idx = s0 + (nco < rem ? nco : rem - 1);
        const int vm = buck[m_idx];
        const float* hrow = emb + (size_t)vm * 64;
        short8 ha[2];
        #pragma unroll
        for (int kt = 0; kt < 2; ++kt) {
            const float4* hv = (const float4*)(hrow + kt * 32 + kr);
            const float4 p = hv[0], q = hv[1];
            short8 t;
            t[0] = f2bf(p.x); t[1] = f2bf(p.y); t[2] = f2bf(p.z); t[3] = f2bf(p.w);
            t[4] = f2bf(q.x); t[5] = f2bf(q.y); t[6] = f2bf(q.z); t[7] = f2bf(q.w);
            ha[kt] = t;
        }

        // hid_pre = H @ W1
        f32x4 acc[4];
        #pragma unroll
        for (int nt = 0; nt < 4; ++nt) {
            acc[nt] = (f32x4){0.f, 0.f, 0.f, 0.f};
            acc[nt] = __builtin_amdgcn_mfma_f32_16x16x32_bf16(ha[0], fw1[nt],     acc[nt], 0, 0, 0);
            acc[nt] = __builtin_amdgcn_mfma_f32_16x16x32_bf16(ha[1], fw1[4 + nt], acc[nt], 0, 0, 0);
        }

        // exact GELU -> bf16 hid in LDS ([m][c] layout, stride 72 avoids conflicts)
        #pragma unroll
        for (int nt = 0; nt < 4; ++nt) {
            #pragma unroll
            for (int i = 0; i < 4; ++i) {
                const float v  = acc[nt][i];
                const float gv = 0.5f * v * (1.0f + erff(v * 0.70710678118f));
                const int  mm  = (lane >> 4) * 4 + i;
                const int  c   = nt * 16 + nco;
                hidb[mm * 72 + c] = f2bf(gv);
            }
        }
        asm volatile("s_waitcnt lgkmcnt(0)" ::: "memory");
        __builtin_amdgcn_sched_barrier(0);   // keep reads below the wait

        // Re-read as A-fragments.
        short8 pa[2];
        #pragma unroll
        for (int kt = 0; kt < 2; ++kt)
            pa[kt] = *(const short8*)&hidb[(lane & 15) * 72 + kt * 32 + kr];

        // corr = gelu(hid) @ W2
        f32x4 acc2[4];
        #pragma unroll
        for (int nt = 0; nt < 4; ++nt) {
            acc2[nt] = (f32x4){0.f, 0.f, 0.f, 0.f};
            acc2[nt] = __builtin_amdgcn_mfma_f32_16x16x32_bf16(pa[0], fw2[nt],     acc2[nt], 0, 0, 0);
            acc2[nt] = __builtin_amdgcn_mfma_f32_16x16x32_bf16(pa[1], fw2[4 + nt], acc2[nt], 0, 0, 0);
        }

        // table[v] = emb[v] + 0.1 * corr
        #pragma unroll
        for (int i = 0; i < 4; ++i) {
            const int mm = (lane >> 4) * 4 + i;
            if (mm < rem) {
                const int vv = buck[s0 + mm];
                const float* hr = emb + (size_t)vv * 64;
                float* trow = table + (size_t)vv * 64;
                #pragma unroll
                for (int nt = 0; nt < 4; ++nt) {
                    const int c = nt * 16 + nco;
                    trow[c] = hr[c] + 0.1f * acc2[nt][i];
                }
            }
        }
    }
}

// Kernel 3: pure gather. out[t] = table[x[t]], 16 lanes x float4 per row.
__global__ __launch_bounds__(256) void k_gather(
    const int* __restrict__ x, const float* __restrict__ table,
    float* __restrict__ out)
{
    const int idx = blockIdx.x * 256 + threadIdx.x;
    const int row = idx >> 4, l16 = idx & 15;
    const int xr  = x[row];
    ((float4*)out)[(size_t)row * 16 + l16] =
        ((const float4*)table)[(size_t)xr * 16 + l16];
}

extern "C" void kernel_launch(void* const* d_in, const int* in_sizes, int n_in,
                              void* d_out, int out_size, void* d_ws, size_t ws_size,
                              hipStream_t stream) {
    const int*   x    = (const int*)d_in[0];
    const int*   tdom = (const int*)d_in[1];
    const float* emb  = (const float*)d_in[2];
    const float* W1   = (const float*)d_in[3];
    const float* W2   = (const float*)d_in[4];
    float* out = (float*)d_out;

    int*   g_cnt  = (int*)d_ws;                              // 16 x 64B lines
    int*   bucket = (int*)((char*)d_ws + 4096);              // 16*CAP*4 = 256 KB
    float* table  = (float*)((char*)d_ws + (1u << 20));      // 12.9 MB

    hipMemsetAsync(d_ws, 0, ND * CNT_STRIDE * sizeof(int), stream);
    hipLaunchKernelGGL(k_vbucket, dim3((VOCABSZ + 255) / 256), dim3(256), 0,
                       stream, tdom, emb, table, g_cnt, bucket);
    hipLaunchKernelGGL(k_vcorrect, dim3(ND * NBLK2), dim3(256), 0, stream,
                       emb, W1, W2, g_cnt, bucket, table);
    hipLaunchKernelGGL(k_gather, dim3(NTOK * 16 / 256), dim3(256), 0, stream,
                       x, table, out);
}

// Round 10
// 108.710 us; speedup vs baseline: 1.0722x; 1.0167x over previous
//
#include <hip/hip_runtime.h>
#include <hip/hip_bf16.h>

#define VOCABSZ 50257
#define BASEDIM 64
#define ND 16
#define NTOK (16 * 8192)
#define CAP 4096            // per-domain vocab bucket capacity (max ~1700 actual)
#define NBLK2 16            // blocks per domain in the MLP kernel (256 total)
#define CNT_STRIDE 16       // counter padding: 16 ints = 64B, one line each

typedef __attribute__((ext_vector_type(8))) short short8;
typedef __attribute__((ext_vector_type(4))) float f32x4;

__device__ __forceinline__ short f2bf(float f) {
    union { float f; unsigned u; } v; v.f = f;
    unsigned r = (v.u + 0x7FFFu + ((v.u >> 16) & 1u)) >> 16;  // RNE f32->bf16
    return (short)r;
}

__device__ __forceinline__ float bf2f(unsigned short b) {
    union { unsigned u; float f; } v; v.u = ((unsigned)b) << 16;
    return v.f;
}

// Kernel 1: bucket VOCAB ids by domain (two-level atomics; padded counters)
// and copy unassigned rows emb[v] -> table16[v] as bf16.
__global__ __launch_bounds__(256) void k_vbucket(
    const int* __restrict__ tdom, const float* __restrict__ emb,
    unsigned short* __restrict__ table16, int* __restrict__ g_cnt,
    int* __restrict__ bucket)
{
    __shared__ int sm_d[256];
    __shared__ int sm_cnt[ND];
    __shared__ int sm_base[ND];

    const int lt = threadIdx.x;
    const int v0 = blockIdx.x * 256;
    const int v  = v0 + lt;

    if (lt < ND) sm_cnt[lt] = 0;
    __syncthreads();

    int d = 0x7fffffff;
    if (v < VOCABSZ) d = tdom[v];
    sm_d[lt] = d;
    int pos = -1;
    if (d < ND) pos = atomicAdd(&sm_cnt[d], 1);
    __syncthreads();

    if (lt < ND) sm_base[lt] = atomicAdd(&g_cnt[lt * CNT_STRIDE], sm_cnt[lt]);
    __syncthreads();

    if (d < ND) {
        const int gp = sm_base[d] + pos;
        if (gp < CAP) bucket[d * CAP + gp] = v;
    }

    // Copy unassigned rows as bf16: 16-lane groups; lane reads float4 (16B),
    // writes short4 (8B). Row = 16 lanes x 8B = 128B contiguous.
    const int g = lt >> 4, l16 = lt & 15;
    const float4* ev = (const float4*)emb;
    #pragma unroll
    for (int it = 0; it < 16; ++it) {
        const int li = it * 16 + g;
        const int vv = v0 + li;
        if (vv < VOCABSZ && sm_d[li] >= ND) {
            const float4 p = ev[(size_t)vv * 16 + l16];
            short4 s;
            s.x = f2bf(p.x); s.y = f2bf(p.y); s.z = f2bf(p.z); s.w = f2bf(p.w);
            *(short4*)&table16[(size_t)vv * 64 + l16 * 4] = s;
        }
    }
}

// Kernel 2: per-domain MLP correction on VOCAB rows via MFMA.
// table16[v] = bf16(emb[v] + 0.1 * W2(gelu(W1 emb[v]))).
__global__ __launch_bounds__(256) void k_vcorrect(
    const float* __restrict__ emb, const float* __restrict__ W1,
    const float* __restrict__ W2, const int* __restrict__ g_cnt,
    const int* __restrict__ bucket, unsigned short* __restrict__ table16)
{
    const int blk   = blockIdx.x;
    const int d     = blk / NBLK2;
    const int chunk = blk % NBLK2;
    int cnt = g_cnt[d * CNT_STRIDE];
    if (cnt > CAP) cnt = CAP;

    const int wave = threadIdx.x >> 6;
    const int lane = threadIdx.x & 63;
    const int kr   = (lane >> 4) * 8;      // k-octet base within a 32-K tile
    const int nco  = lane & 15;

    __shared__ float sw[2][4096];                      // W1,W2 raw fp32 (32 KB)
    __shared__ __align__(16) short sm_hid[4][16 * 72]; // hid staging (9 KB)

    // Coalesced cooperative weight load: 1024 float4 per matrix.
    {
        const float4* w1v = (const float4*)(W1 + (size_t)d * 4096);
        const float4* w2v = (const float4*)(W2 + (size_t)d * 4096);
        float4* s1 = (float4*)sw[0];
        float4* s2 = (float4*)sw[1];
        for (int i = threadIdx.x; i < 1024; i += 256) {
            s1[i] = w1v[i];
            s2[i] = w2v[i];
        }
    }
    __syncthreads();

    // Extract MFMA B-fragments (bf16) from LDS. 64 VGPRs total.
    short8 fw1[8], fw2[8];
    #pragma unroll
    for (int kt = 0; kt < 2; ++kt) {
        #pragma unroll
        for (int nt = 0; nt < 4; ++nt) {
            short8 a, b;
            #pragma unroll
            for (int i = 0; i < 8; ++i) {
                const int k = kt * 32 + kr + i;
                const int n = nt * 16 + nco;
                a[i] = f2bf(sw[0][k * 64 + n]);
                b[i] = f2bf(sw[1][k * 64 + n]);
            }
            fw1[kt * 4 + nt] = a;
            fw2[kt * 4 + nt] = b;
        }
    }

    short* hidb = &sm_hid[wave][0];
    const int* buck = bucket + (size_t)d * CAP;

    for (int base = chunk * 64; base < cnt; base += NBLK2 * 64) {
        const int s0 = base + wave * 16;
        int rem = cnt - s0;
        if (rem <= 0) continue;            // per-wave; no barriers in loop
        if (rem > 16) rem = 16;

        // Gather emb rows as A-fragments (row m = lane&15).
        const int m_idx = s0 + (nco < rem ? nco : rem - 1);
        const int vm = buck[m_idx];
        const float* hrow = emb + (size_t)vm * 64;
        short8 ha[2];
        #pragma unroll
        for (int kt = 0; kt < 2; ++kt) {
            const float4* hv = (const float4*)(hrow + kt * 32 + kr);
            const float4 p = hv[0], q = hv[1];
            short8 t;
            t[0] = f2bf(p.x); t[1] = f2bf(p.y); t[2] = f2bf(p.z); t[3] = f2bf(p.w);
            t[4] = f2bf(q.x); t[5] = f2bf(q.y); t[6] = f2bf(q.z); t[7] = f2bf(q.w);
            ha[kt] = t;
        }

        // hid_pre = H @ W1
        f32x4 acc[4];
        #pragma unroll
        for (int nt = 0; nt < 4; ++nt) {
            acc[nt] = (f32x4){0.f, 0.f, 0.f, 0.f};
            acc[nt] = __builtin_amdgcn_mfma_f32_16x16x32_bf16(ha[0], fw1[nt],     acc[nt], 0, 0, 0);
            acc[nt] = __builtin_amdgcn_mfma_f32_16x16x32_bf16(ha[1], fw1[4 + nt], acc[nt], 0, 0, 0);
        }

        // exact GELU -> bf16 hid in LDS ([m][c] layout, stride 72 avoids conflicts)
        #pragma unroll
        for (int nt = 0; nt < 4; ++nt) {
            #pragma unroll
            for (int i = 0; i < 4; ++i) {
                const float v  = acc[nt][i];
                const float gv = 0.5f * v * (1.0f + erff(v * 0.70710678118f));
                const int  mm  = (lane >> 4) * 4 + i;
                const int  c   = nt * 16 + nco;
                hidb[mm * 72 + c] = f2bf(gv);
            }
        }
        asm volatile("s_waitcnt lgkmcnt(0)" ::: "memory");
        __builtin_amdgcn_sched_barrier(0);   // keep reads below the wait

        // Re-read as A-fragments.
        short8 pa[2];
        #pragma unroll
        for (int kt = 0; kt < 2; ++kt)
            pa[kt] = *(const short8*)&hidb[(lane & 15) * 72 + kt * 32 + kr];

        // corr = gelu(hid) @ W2
        f32x4 acc2[4];
        #pragma unroll
        for (int nt = 0; nt < 4; ++nt) {
            acc2[nt] = (f32x4){0.f, 0.f, 0.f, 0.f};
            acc2[nt] = __builtin_amdgcn_mfma_f32_16x16x32_bf16(pa[0], fw2[nt],     acc2[nt], 0, 0, 0);
            acc2[nt] = __builtin_amdgcn_mfma_f32_16x16x32_bf16(pa[1], fw2[4 + nt], acc2[nt], 0, 0, 0);
        }

        // table16[v] = bf16(emb[v] + 0.1 * corr)
        #pragma unroll
        for (int i = 0; i < 4; ++i) {
            const int mm = (lane >> 4) * 4 + i;
            if (mm < rem) {
                const int vv = buck[s0 + mm];
                const float* hr = emb + (size_t)vv * 64;
                unsigned short* trow = table16 + (size_t)vv * 64;
                #pragma unroll
                for (int nt = 0; nt < 4; ++nt) {
                    const int c = nt * 16 + nco;
                    trow[c] = (unsigned short)f2bf(hr[c] + 0.1f * acc2[nt][i]);
                }
            }
        }
    }
}

// Kernel 3: gather + widen. out[t] = f32(table16[x[t]]).
// 8 lanes per row: lane reads short8 (16B), writes 2x float4 (32B).
__global__ __launch_bounds__(256) void k_gather(
    const int* __restrict__ x, const unsigned short* __restrict__ table16,
    float* __restrict__ out)
{
    const int stride = gridDim.x * 256;
    for (int u = blockIdx.x * 256 + threadIdx.x; u < NTOK * 8; u += stride) {
        const int row = u >> 3, l8 = u & 7;
        const int xr  = x[row];
        const short8 v = *(const short8*)&table16[(size_t)xr * 64 + l8 * 8];
        float4 a, b;
        a.x = bf2f((unsigned short)v[0]); a.y = bf2f((unsigned short)v[1]);
        a.z = bf2f((unsigned short)v[2]); a.w = bf2f((unsigned short)v[3]);
        b.x = bf2f((unsigned short)v[4]); b.y = bf2f((unsigned short)v[5]);
        b.z = bf2f((unsigned short)v[6]); b.w = bf2f((unsigned short)v[7]);
        float4* orow = (float4*)(out + (size_t)row * 64 + l8 * 8);
        orow[0] = a;
        orow[1] = b;
    }
}

extern "C" void kernel_launch(void* const* d_in, const int* in_sizes, int n_in,
                              void* d_out, int out_size, void* d_ws, size_t ws_size,
                              hipStream_t stream) {
    const int*   x    = (const int*)d_in[0];
    const int*   tdom = (const int*)d_in[1];
    const float* emb  = (const float*)d_in[2];
    const float* W1   = (const float*)d_in[3];
    const float* W2   = (const float*)d_in[4];
    float* out = (float*)d_out;

    int*            g_cnt   = (int*)d_ws;                         // 16 x 64B lines
    int*            bucket  = (int*)((char*)d_ws + 4096);         // 256 KB
    unsigned short* table16 = (unsigned short*)((char*)d_ws + (1u << 20)); // 6.4 MB

    hipMemsetAsync(d_ws, 0, ND * CNT_STRIDE * sizeof(int), stream);
    hipLaunchKernelGGL(k_vbucket, dim3((VOCABSZ + 255) / 256), dim3(256), 0,
                       stream, tdom, emb, table16, g_cnt, bucket);
    hipLaunchKernelGGL(k_vcorrect, dim3(ND * NBLK2), dim3(256), 0, stream,
                       emb, W1, W2, g_cnt, bucket, table16);
    hipLaunchKernelGGL(k_gather, dim3(2048), dim3(256), 0, stream,
                       x, table16, out);
}

// Round 15
// 98.155 us; speedup vs baseline: 1.1875x; 1.1075x over previous
//
#include <hip/hip_runtime.h>
#include <hip/hip_bf16.h>

#define VOCABSZ 50257
#define BASEDIM 64
#define ND 16
#define NTOK (16 * 8192)
#define NCLS 32
#define LCAP 128

typedef __attribute__((ext_vector_type(8))) short short8;
typedef __attribute__((ext_vector_type(4))) float f32x4;

__device__ __forceinline__ short f2bf(float f) {
    union { float f; unsigned u; } v; v.f = f;
    unsigned r = (v.u + 0x7FFFu + ((v.u >> 16) & 1u)) >> 16;
    return (short)r;
}

__device__ __forceinline__ float bf2f(unsigned short b) {
    union { unsigned u; float f; } v; v.u = ((unsigned)b) << 16;
    return v.f;
}

// Kernel 1: self-scanning per-domain MLP correction. Block (d,c) scans vocab
// ids v == c (mod 32), keeps those with tdom[v]==d in an LDS list (order
// irrelevant, so a plain LDS atomic suffices), then runs the MFMA pipeline:
// table16[v] = bf16(emb[v] + 0.1 * W2(gelu(W1 emb[v]))).
// No global atomics, no bucket array, no memset dependency.
__global__ __launch_bounds__(256) void k_vcorrect(
    const int* __restrict__ tdom, const float* __restrict__ emb,
    const float* __restrict__ W1, const float* __restrict__ W2,
    unsigned short* __restrict__ table16)
{
    const int blk = blockIdx.x;
    const int d   = blk >> 5;            // domain
    const int c   = blk & (NCLS - 1);    // vocab stride class

    const int lt   = threadIdx.x;
    const int wave = lt >> 6;
    const int lane = lt & 63;
    const int kr   = (lane >> 4) * 8;    // k-octet base within a 32-K tile
    const int nco  = lane & 15;

    __shared__ float sw[2][4096];                      // W1,W2 raw fp32 (32 KB)
    __shared__ __align__(16) short sm_hid[4][16 * 72]; // hid staging (9 KB)
    __shared__ int list[LCAP];
    __shared__ int lcnt;

    if (lt == 0) lcnt = 0;

    // Stage weights (coalesced float4).
    {
        const float4* w1v = (const float4*)(W1 + (size_t)d * 4096);
        const float4* w2v = (const float4*)(W2 + (size_t)d * 4096);
        float4* s1 = (float4*)sw[0];
        float4* s2 = (float4*)sw[1];
        #pragma unroll
        for (int i = 0; i < 4; ++i) {
            s1[lt + 256 * i] = w1v[lt + 256 * i];
            s2[lt + 256 * i] = w2v[lt + 256 * i];
        }
    }
    __syncthreads();   // lcnt=0 visible; weights in LDS

    // Scan my stride class: v = c, c+32, c+64, ...
    for (int i = lt; i * NCLS + c < VOCABSZ; i += 256) {
        const int v = i * NCLS + c;
        if (tdom[v] == d) {
            const int p = atomicAdd(&lcnt, 1);
            if (p < LCAP) list[p] = v;
        }
    }
    __syncthreads();

    int cnt = lcnt;
    if (cnt > LCAP) cnt = LCAP;

    // Extract MFMA B-fragments (bf16) from LDS. 64 VGPRs total.
    short8 fw1[8], fw2[8];
    #pragma unroll
    for (int kt = 0; kt < 2; ++kt) {
        #pragma unroll
        for (int nt = 0; nt < 4; ++nt) {
            short8 a, b;
            #pragma unroll
            for (int i = 0; i < 8; ++i) {
                const int k = kt * 32 + kr + i;
                const int n = nt * 16 + nco;
                a[i] = f2bf(sw[0][k * 64 + n]);
                b[i] = f2bf(sw[1][k * 64 + n]);
            }
            fw1[kt * 4 + nt] = a;
            fw2[kt * 4 + nt] = b;
        }
    }

    short* hidb = &sm_hid[wave][0];

    for (int base = 0; base < cnt; base += 64) {
        const int s0 = base + wave * 16;
        int rem = cnt - s0;
        if (rem <= 0) continue;            // per-wave; no barriers in loop
        if (rem > 16) rem = 16;

        // Gather emb rows as A-fragments (row m = lane&15).
        const int m_idx = s0 + (nco < rem ? nco : rem - 1);
        const int vm = list[m_idx];
        const float* hrow = emb + (size_t)vm * 64;
        short8 ha[2];
        #pragma unroll
        for (int kt = 0; kt < 2; ++kt) {
            const float4* hv = (const float4*)(hrow + kt * 32 + kr);
            const float4 p = hv[0], q = hv[1];
            short8 t;
            t[0] = f2bf(p.x); t[1] = f2bf(p.y); t[2] = f2bf(p.z); t[3] = f2bf(p.w);
            t[4] = f2bf(q.x); t[5] = f2bf(q.y); t[6] = f2bf(q.z); t[7] = f2bf(q.w);
            ha[kt] = t;
        }

        // hid_pre = H @ W1
        f32x4 acc[4];
        #pragma unroll
        for (int nt = 0; nt < 4; ++nt) {
            acc[nt] = (f32x4){0.f, 0.f, 0.f, 0.f};
            acc[nt] = __builtin_amdgcn_mfma_f32_16x16x32_bf16(ha[0], fw1[nt],     acc[nt], 0, 0, 0);
            acc[nt] = __builtin_amdgcn_mfma_f32_16x16x32_bf16(ha[1], fw1[4 + nt], acc[nt], 0, 0, 0);
        }

        // exact GELU -> bf16 hid in LDS ([m][c] layout, stride 72 avoids conflicts)
        #pragma unroll
        for (int nt = 0; nt < 4; ++nt) {
            #pragma unroll
            for (int i = 0; i < 4; ++i) {
                const float v  = acc[nt][i];
                const float gv = 0.5f * v * (1.0f + erff(v * 0.70710678118f));
                const int  mm  = (lane >> 4) * 4 + i;
                const int  cc  = nt * 16 + nco;
                hidb[mm * 72 + cc] = f2bf(gv);
            }
        }
        asm volatile("s_waitcnt lgkmcnt(0)" ::: "memory");
        __builtin_amdgcn_sched_barrier(0);   // keep reads below the wait

        // Re-read as A-fragments.
        short8 pa[2];
        #pragma unroll
        for (int kt = 0; kt < 2; ++kt)
            pa[kt] = *(const short8*)&hidb[(lane & 15) * 72 + kt * 32 + kr];

        // corr = gelu(hid) @ W2
        f32x4 acc2[4];
        #pragma unroll
        for (int nt = 0; nt < 4; ++nt) {
            acc2[nt] = (f32x4){0.f, 0.f, 0.f, 0.f};
            acc2[nt] = __builtin_amdgcn_mfma_f32_16x16x32_bf16(pa[0], fw2[nt],     acc2[nt], 0, 0, 0);
            acc2[nt] = __builtin_amdgcn_mfma_f32_16x16x32_bf16(pa[1], fw2[4 + nt], acc2[nt], 0, 0, 0);
        }

        // table16[v] = bf16(emb[v] + 0.1 * corr)
        #pragma unroll
        for (int i = 0; i < 4; ++i) {
            const int mm = (lane >> 4) * 4 + i;
            if (mm < rem) {
                const int vv = list[s0 + mm];
                const float* hr = emb + (size_t)vv * 64;
                unsigned short* trow = table16 + (size_t)vv * 64;
                #pragma unroll
                for (int nt = 0; nt < 4; ++nt) {
                    const int cc = nt * 16 + nco;
                    trow[cc] = (unsigned short)f2bf(hr[cc] + 0.1f * acc2[nt][i]);
                }
            }
        }
    }
}

// Kernel 2: dual-path gather. 8 lanes/row.
//   assigned (tdom[xr] < ND):  out = f32(table16[xr])   (128B/row)
//   unassigned:                out = emb[xr]            (256B/row, exact fp32)
__global__ __launch_bounds__(256) void k_gather(
    const int* __restrict__ x, const int* __restrict__ tdom,
    const float* __restrict__ emb, const unsigned short* __restrict__ table16,
    float* __restrict__ out)
{
    const int stride = gridDim.x * 256;
    for (int u = blockIdx.x * 256 + threadIdx.x; u < NTOK * 8; u += stride) {
        const int row = u >> 3, l8 = u & 7;
        const int xr  = x[row];
        float4 a, b;
        if (tdom[xr] < ND) {
            const short8 v = *(const short8*)&table16[(size_t)xr * 64 + l8 * 8];
            a.x = bf2f((unsigned short)v[0]); a.y = bf2f((unsigned short)v[1]);
            a.z = bf2f((unsigned short)v[2]); a.w = bf2f((unsigned short)v[3]);
            b.x = bf2f((unsigned short)v[4]); b.y = bf2f((unsigned short)v[5]);
            b.z = bf2f((unsigned short)v[6]); b.w = bf2f((unsigned short)v[7]);
        } else {
            const float4* ev = (const float4*)(emb + (size_t)xr * 64 + l8 * 8);
            a = ev[0];
            b = ev[1];
        }
        float4* orow = (float4*)(out + (size_t)row * 64 + l8 * 8);
        orow[0] = a;
        orow[1] = b;
    }
}

extern "C" void kernel_launch(void* const* d_in, const int* in_sizes, int n_in,
                              void* d_out, int out_size, void* d_ws, size_t ws_size,
                              hipStream_t stream) {
    const int*   x    = (const int*)d_in[0];
    const int*   tdom = (const int*)d_in[1];
    const float* emb  = (const float*)d_in[2];
    const float* W1   = (const float*)d_in[3];
    const float* W2   = (const float*)d_in[4];
    float* out = (float*)d_out;

    unsigned short* table16 = (unsigned short*)d_ws;   // 6.43 MB of ws

    hipLaunchKernelGGL(k_vcorrect, dim3(ND * NCLS), dim3(256), 0, stream,
                       tdom, emb, W1, W2, table16);
    hipLaunchKernelGGL(k_gather, dim3(2048), dim3(256), 0, stream,
                       x, tdom, emb, table16, out);
}